// Round 1
// baseline (123.816 us; speedup 1.0000x reference)
//
#include <hip/hip_runtime.h>

#define H 1536
#define BD 128
#define ROWS 16
#define NTHREADS 512
#define NBLOCKS 1024   // 16384 rows / 16

using f16x8 = _Float16 __attribute__((ext_vector_type(8)));
using f32x4 = float __attribute__((ext_vector_type(4)));

// ---------------------------------------------------------------------------
// Kernel 0: convert weights fp32 -> fp16 into workspace
// wd16: [128][1536] row-major (W_down as given), wu16: [1536][128] row-major
// ---------------------------------------------------------------------------
__global__ __launch_bounds__(256) void convert_weights(const float* __restrict__ wd,
                                                       const float* __restrict__ wu,
                                                       _Float16* __restrict__ wd16,
                                                       _Float16* __restrict__ wu16) {
    int t = blockIdx.x * 256 + threadIdx.x;  // 0 .. 393215
    if (t < 128 * H) {
        wd16[t] = (_Float16)wd[t];
    } else {
        int u = t - 128 * H;
        wu16[u] = (_Float16)wu[u];
    }
}

// ---------------------------------------------------------------------------
// Fused: down_proj -> (fourier == identity) -> up_proj -> +residual -> LN
// One block = 16 rows. hs tile lives in LDS as fp16 (XOR-swizzled), is
// overwritten in place with y = hs + x, then normalized and written out.
// MFMA 16x16x32 f16 fragment mapping (guide §3, m89/m91 verified):
//   A: m = lane&15, k = 8*(lane>>4)+b   (8 contiguous k per lane)
//   B: n = lane&15, k = 8*(lane>>4)+b   (loaded from B^T rows)
//   D: n = lane&15, m = 4*(lane>>4)+reg
// ---------------------------------------------------------------------------
__global__ __launch_bounds__(NTHREADS, 4) void fused_adapter(
    const float* __restrict__ hs,
    const _Float16* __restrict__ wd16,
    const _Float16* __restrict__ wu16,
    const float* __restrict__ gamma,
    const float* __restrict__ beta,
    float* __restrict__ out)
{
    __shared__ alignas(16) _Float16 hsb[ROWS * H];    // 48 KiB, hs then y
    __shared__ alignas(16) _Float16 tb[ROWS * BD];    // 4 KiB, bottleneck t
    __shared__ float redS[8 * ROWS];
    __shared__ float redQ[8 * ROWS];
    __shared__ float statsM[ROWS];
    __shared__ float statsR[ROWS];

    const int tid  = threadIdx.x;
    const int lane = tid & 63;
    const int w    = tid >> 6;        // wave 0..7
    const int l15  = lane & 15;
    const int lk   = lane >> 4;       // 0..3
    const long row0 = (long)blockIdx.x * ROWS;

    // ---- stage hs tile -> LDS fp16, swizzled: idx = r*H + (col ^ ((r&7)<<3))
    const float* hsblk = hs + row0 * H;
#pragma unroll
    for (int i = 0; i < 6; ++i) {
        int c  = tid + NTHREADS * i;          // 0..3071 chunk id (8 elems each)
        int r  = c / 192;
        int c8 = c - r * 192;
        int col = c8 * 8;
        const float4* p = reinterpret_cast<const float4*>(hsblk + (long)r * H + col);
        float4 v0 = p[0];
        float4 v1 = p[1];
        f16x8 hv;
        hv[0] = (_Float16)v0.x; hv[1] = (_Float16)v0.y;
        hv[2] = (_Float16)v0.z; hv[3] = (_Float16)v0.w;
        hv[4] = (_Float16)v1.x; hv[5] = (_Float16)v1.y;
        hv[6] = (_Float16)v1.z; hv[7] = (_Float16)v1.w;
        *reinterpret_cast<f16x8*>(&hsb[r * H + (col ^ ((r & 7) << 3))]) = hv;
    }
    __syncthreads();

    // ---- GEMM1: t[16][128] = hs_tile @ Wd^T.  Wave w owns t-cols 16w..16w+15.
    f32x4 acc1a = {0.f, 0.f, 0.f, 0.f};
    f32x4 acc1b = {0.f, 0.f, 0.f, 0.f};
    {
        const _Float16* wdrow = wd16 + (long)(16 * w + l15) * H + 8 * lk;
        const int arow = l15 * H;
        const int aswz = (l15 & 7) << 3;
#pragma unroll 2
        for (int kf2 = 0; kf2 < 24; ++kf2) {
            int k0 = 8 * lk + 64 * kf2;
            f16x8 a0 = *reinterpret_cast<const f16x8*>(&hsb[arow + (k0 ^ aswz)]);
            f16x8 b0 = *reinterpret_cast<const f16x8*>(wdrow + 64 * kf2);
            acc1a = __builtin_amdgcn_mfma_f32_16x16x32_f16(a0, b0, acc1a, 0, 0, 0);
            f16x8 a1 = *reinterpret_cast<const f16x8*>(&hsb[arow + ((k0 + 32) ^ aswz)]);
            f16x8 b1 = *reinterpret_cast<const f16x8*>(wdrow + 64 * kf2 + 32);
            acc1b = __builtin_amdgcn_mfma_f32_16x16x32_f16(a1, b1, acc1b, 0, 0, 0);
        }
    }
    {
        f32x4 acc1 = acc1a + acc1b;
        int tcol = 16 * w + l15;
#pragma unroll
        for (int j = 0; j < 4; ++j) {
            int r = 4 * lk + j;
            tb[r * BD + (tcol ^ ((r & 7) << 3))] = (_Float16)acc1[j];
        }
    }
    __syncthreads();

    // ---- GEMM2 + residual + per-row partial stats. Wave w owns out-cols 192w..
    f16x8 a2[4];
#pragma unroll
    for (int kf = 0; kf < 4; ++kf) {
        int kcol = 8 * lk + 32 * kf;
        a2[kf] = *reinterpret_cast<const f16x8*>(&tb[l15 * BD + (kcol ^ ((l15 & 7) << 3))]);
    }
    float sums[4] = {0.f, 0.f, 0.f, 0.f};
    float sumq[4] = {0.f, 0.f, 0.f, 0.f};
#pragma unroll 2
    for (int nf = 0; nf < 12; ++nf) {
        int cn = 192 * w + 16 * nf + l15;
        const _Float16* wurow = wu16 + (long)cn * BD + 8 * lk;
        f32x4 acc = {0.f, 0.f, 0.f, 0.f};
#pragma unroll
        for (int kf = 0; kf < 4; ++kf) {
            f16x8 b = *reinterpret_cast<const f16x8*>(wurow + 32 * kf);
            acc = __builtin_amdgcn_mfma_f32_16x16x32_f16(a2[kf], b, acc, 0, 0, 0);
        }
#pragma unroll
        for (int j = 0; j < 4; ++j) {
            int r = 4 * lk + j;
            int idx = r * H + (cn ^ ((r & 7) << 3));
            float y = acc[j] + (float)hsb[idx];
            sums[j] += y;
            sumq[j] += y * y;
            hsb[idx] = (_Float16)y;      // y overwrites hs in place
        }
    }

    // ---- reduce stats: over 16 low lanes (cols), then across 8 waves via LDS
#pragma unroll
    for (int j = 0; j < 4; ++j) {
#pragma unroll
        for (int off = 1; off < 16; off <<= 1) {
            sums[j] += __shfl_xor(sums[j], off);
            sumq[j] += __shfl_xor(sumq[j], off);
        }
    }
    if (l15 == 0) {
#pragma unroll
        for (int j = 0; j < 4; ++j) {
            int r = 4 * lk + j;
            redS[w * ROWS + r] = sums[j];
            redQ[w * ROWS + r] = sumq[j];
        }
    }
    __syncthreads();
    if (tid < ROWS) {
        float S = 0.f, Q = 0.f;
#pragma unroll
        for (int ww = 0; ww < 8; ++ww) {
            S += redS[ww * ROWS + tid];
            Q += redQ[ww * ROWS + tid];
        }
        float mean = S * (1.0f / (float)H);
        float var  = Q * (1.0f / (float)H) - mean * mean;
        statsM[tid] = mean;
        statsR[tid] = rsqrtf(var + 1e-5f);
    }
    __syncthreads();

    // ---- normalize + write out (coalesced float4 x2 per thread-chunk)
#pragma unroll
    for (int i = 0; i < 6; ++i) {
        int c  = tid + NTHREADS * i;
        int r  = c / 192;
        int c8 = c - r * 192;
        int col = c8 * 8;
        f16x8 yv = *reinterpret_cast<const f16x8*>(&hsb[r * H + (col ^ ((r & 7) << 3))]);
        float mean = statsM[r];
        float rstd = statsR[r];
        const float4* gp = reinterpret_cast<const float4*>(gamma + col);
        const float4* bp = reinterpret_cast<const float4*>(beta + col);
        float4 g0 = gp[0], g1 = gp[1];
        float4 b0 = bp[0], b1 = bp[1];
        float4 o0, o1;
        o0.x = ((float)yv[0] - mean) * rstd * g0.x + b0.x;
        o0.y = ((float)yv[1] - mean) * rstd * g0.y + b0.y;
        o0.z = ((float)yv[2] - mean) * rstd * g0.z + b0.z;
        o0.w = ((float)yv[3] - mean) * rstd * g0.w + b0.w;
        o1.x = ((float)yv[4] - mean) * rstd * g1.x + b1.x;
        o1.y = ((float)yv[5] - mean) * rstd * g1.y + b1.y;
        o1.z = ((float)yv[6] - mean) * rstd * g1.z + b1.z;
        o1.w = ((float)yv[7] - mean) * rstd * g1.w + b1.w;
        float4* op = reinterpret_cast<float4*>(out + (row0 + r) * H + col);
        op[0] = o0;
        op[1] = o1;
    }
}

extern "C" void kernel_launch(void* const* d_in, const int* in_sizes, int n_in,
                              void* d_out, int out_size, void* d_ws, size_t ws_size,
                              hipStream_t stream) {
    const float* hs    = (const float*)d_in[0];
    const float* wd    = (const float*)d_in[1];
    const float* wu    = (const float*)d_in[2];
    const float* gam   = (const float*)d_in[3];
    const float* bet   = (const float*)d_in[4];
    float* out = (float*)d_out;

    _Float16* wd16 = (_Float16*)d_ws;
    _Float16* wu16 = (_Float16*)((char*)d_ws + (size_t)128 * H * sizeof(_Float16));

    convert_weights<<<1536, 256, 0, stream>>>(wd, wu, wd16, wu16);
    fused_adapter<<<NBLOCKS, NTHREADS, 0, stream>>>(hs, wd16, wu16, gam, bet, out);
}

// Round 2
// 72.833 us; speedup vs baseline: 1.7000x; 1.7000x over previous
//
#include <hip/hip_runtime.h>

#define H 1536
#define BD 128
#define ROWS 16
#define NTHREADS 512
#define NBLOCKS 1024   // 16384 rows / 16

using f16x8 = _Float16 __attribute__((ext_vector_type(8)));
using f32x4 = float __attribute__((ext_vector_type(4)));

// ---------------------------------------------------------------------------
// Kernel 0: pack weights fp32 -> fp16 in MFMA B-fragment order.
//   wdp: frag f = (w*48 + kk)*64 + l  holds Wd[16w + (l&15)][32*kk + 8*(l>>4) + e]
//   wup: frag g = (w*48 + nf*4+kf)*64 + l holds Wu[192w + 16nf + (l&15)][32*kf + 8*(l>>4) + e]
// Every hot-loop weight load becomes base + lane*16B (single coalesced 1KB).
// ---------------------------------------------------------------------------
__global__ __launch_bounds__(256) void pack_weights(const float* __restrict__ wd,
                                                    const float* __restrict__ wu,
                                                    _Float16* __restrict__ wdp,
                                                    _Float16* __restrict__ wup) {
    int f = blockIdx.x * 256 + threadIdx.x;   // 0..49151
    const float* src;
    _Float16* dst;
    if (f < 24576) {
        int w = f / 3072, rem = f - w * 3072;
        int kk = rem >> 6, l = rem & 63;
        int row = 16 * w + (l & 15);
        int col = 32 * kk + 8 * (l >> 4);
        src = wd + (size_t)row * H + col;     // Wd is [128][1536]
        dst = wdp + (size_t)f * 8;
    } else {
        int g = f - 24576;
        int w = g / 3072, rem = g - w * 3072;
        int t = rem >> 6, l = rem & 63;       // t = nf*4 + kf
        int nf = t >> 2, kf = t & 3;
        int row = 192 * w + 16 * nf + (l & 15);
        int col = 32 * kf + 8 * (l >> 4);
        src = wu + (size_t)row * BD + col;    // Wu is [1536][128]
        dst = wup + (size_t)g * 8;
    }
    float4 v0 = reinterpret_cast<const float4*>(src)[0];
    float4 v1 = reinterpret_cast<const float4*>(src)[1];
    f16x8 h;
    h[0] = (_Float16)v0.x; h[1] = (_Float16)v0.y;
    h[2] = (_Float16)v0.z; h[3] = (_Float16)v0.w;
    h[4] = (_Float16)v1.x; h[5] = (_Float16)v1.y;
    h[6] = (_Float16)v1.z; h[7] = (_Float16)v1.w;
    *reinterpret_cast<f16x8*>(dst) = h;
}

// ---------------------------------------------------------------------------
// Fused: down_proj -> (fourier == identity) -> up_proj -> +residual -> LN
// One block = 16 rows; hs tile in LDS fp16 (XOR-swizzled), overwritten by y.
// MFMA 16x16x32 f16 mapping: A/B lane l: idx=(l&15), k=8*(l>>4)+e; D: n=l&15,
// m=4*(l>>4)+reg.
// ---------------------------------------------------------------------------
__global__ __launch_bounds__(NTHREADS, 4) void fused_adapter(
    const float* __restrict__ hs,
    const _Float16* __restrict__ wdp,
    const _Float16* __restrict__ wup,
    const float* __restrict__ gamma,
    const float* __restrict__ beta,
    float* __restrict__ out)
{
    __shared__ alignas(16) _Float16 hsb[ROWS * H];    // 48 KiB, hs then y
    __shared__ alignas(16) _Float16 tb[ROWS * BD];    // 4 KiB, bottleneck t
    __shared__ float redS[8 * ROWS];
    __shared__ float redQ[8 * ROWS];
    __shared__ float statsM[ROWS];
    __shared__ float statsR[ROWS];

    const int tid  = threadIdx.x;
    const int lane = tid & 63;
    const int w    = tid >> 6;        // wave 0..7
    const int l15  = lane & 15;
    const int lk   = lane >> 4;       // 0..3
    const long row0 = (long)blockIdx.x * ROWS;

    // ---- stage hs tile -> LDS fp16, swizzled: idx = r*H + (col ^ ((r&7)<<3))
    const float* hsblk = hs + row0 * H;
#pragma unroll
    for (int i = 0; i < 6; ++i) {
        int c  = tid + NTHREADS * i;          // chunk id (8 elems each)
        int r  = c / 192;
        int c8 = c - r * 192;
        int col = c8 * 8;
        const float4* p = reinterpret_cast<const float4*>(hsblk + (long)r * H + col);
        float4 v0 = p[0];
        float4 v1 = p[1];
        f16x8 hv;
        hv[0] = (_Float16)v0.x; hv[1] = (_Float16)v0.y;
        hv[2] = (_Float16)v0.z; hv[3] = (_Float16)v0.w;
        hv[4] = (_Float16)v1.x; hv[5] = (_Float16)v1.y;
        hv[6] = (_Float16)v1.z; hv[7] = (_Float16)v1.w;
        *reinterpret_cast<f16x8*>(&hsb[r * H + (col ^ ((r & 7) << 3))]) = hv;
    }
    __syncthreads();

    // ---- GEMM1: t[16][128] = hs_tile @ Wd^T.  Wave w owns t-cols 16w..16w+15.
    // B loads are fully coalesced from packed wdp (lane*16B within 1KB frags).
    {
        f32x4 acc0 = {0.f,0.f,0.f,0.f}, acc1 = {0.f,0.f,0.f,0.f};
        f32x4 acc2 = {0.f,0.f,0.f,0.f}, acc3 = {0.f,0.f,0.f,0.f};
        const _Float16* wp = wdp + ((size_t)w * 48 * 64 + lane) * 8;
        const int arow = l15 * H;
        const int aswz = (l15 & 7) << 3;
#pragma unroll
        for (int kk = 0; kk < 48; kk += 4) {
            f16x8 b0 = *reinterpret_cast<const f16x8*>(wp + (size_t)(kk + 0) * 512);
            f16x8 b1 = *reinterpret_cast<const f16x8*>(wp + (size_t)(kk + 1) * 512);
            f16x8 b2 = *reinterpret_cast<const f16x8*>(wp + (size_t)(kk + 2) * 512);
            f16x8 b3 = *reinterpret_cast<const f16x8*>(wp + (size_t)(kk + 3) * 512);
            f16x8 a0 = *reinterpret_cast<const f16x8*>(&hsb[arow + ((8*lk + 32*(kk+0)) ^ aswz)]);
            f16x8 a1 = *reinterpret_cast<const f16x8*>(&hsb[arow + ((8*lk + 32*(kk+1)) ^ aswz)]);
            f16x8 a2 = *reinterpret_cast<const f16x8*>(&hsb[arow + ((8*lk + 32*(kk+2)) ^ aswz)]);
            f16x8 a3 = *reinterpret_cast<const f16x8*>(&hsb[arow + ((8*lk + 32*(kk+3)) ^ aswz)]);
            acc0 = __builtin_amdgcn_mfma_f32_16x16x32_f16(a0, b0, acc0, 0, 0, 0);
            acc1 = __builtin_amdgcn_mfma_f32_16x16x32_f16(a1, b1, acc1, 0, 0, 0);
            acc2 = __builtin_amdgcn_mfma_f32_16x16x32_f16(a2, b2, acc2, 0, 0, 0);
            acc3 = __builtin_amdgcn_mfma_f32_16x16x32_f16(a3, b3, acc3, 0, 0, 0);
        }
        f32x4 acc = (acc0 + acc1) + (acc2 + acc3);
        int tcol = 16 * w + l15;
#pragma unroll
        for (int j = 0; j < 4; ++j) {
            int r = 4 * lk + j;
            tb[r * BD + (tcol ^ ((r & 7) << 3))] = (_Float16)acc[j];
        }
    }
    __syncthreads();

    // ---- GEMM2 + residual + per-row partial stats. Wave w owns out-cols 192w..
    f16x8 a2f[4];
#pragma unroll
    for (int kf = 0; kf < 4; ++kf) {
        int kcol = 8 * lk + 32 * kf;
        a2f[kf] = *reinterpret_cast<const f16x8*>(&tb[l15 * BD + (kcol ^ ((l15 & 7) << 3))]);
    }
    float sums[4] = {0.f, 0.f, 0.f, 0.f};
    float sumq[4] = {0.f, 0.f, 0.f, 0.f};
    const _Float16* up = wup + ((size_t)w * 48 * 64 + lane) * 8;
#pragma unroll 2
    for (int nf = 0; nf < 12; ++nf) {
        int cn = 192 * w + 16 * nf + l15;
        f32x4 acc = {0.f, 0.f, 0.f, 0.f};
#pragma unroll
        for (int kf = 0; kf < 4; ++kf) {
            f16x8 b = *reinterpret_cast<const f16x8*>(up + (size_t)(nf * 4 + kf) * 512);
            acc = __builtin_amdgcn_mfma_f32_16x16x32_f16(a2f[kf], b, acc, 0, 0, 0);
        }
#pragma unroll
        for (int j = 0; j < 4; ++j) {
            int r = 4 * lk + j;
            int idx = r * H + (cn ^ ((r & 7) << 3));
            float y = acc[j] + (float)hsb[idx];
            sums[j] += y;
            sumq[j] += y * y;
            hsb[idx] = (_Float16)y;      // y overwrites hs in place
        }
    }

    // ---- reduce stats: 16 low lanes (cols), then across 8 waves via LDS
#pragma unroll
    for (int j = 0; j < 4; ++j) {
#pragma unroll
        for (int off = 1; off < 16; off <<= 1) {
            sums[j] += __shfl_xor(sums[j], off);
            sumq[j] += __shfl_xor(sumq[j], off);
        }
    }
    if (l15 == 0) {
#pragma unroll
        for (int j = 0; j < 4; ++j) {
            int r = 4 * lk + j;
            redS[w * ROWS + r] = sums[j];
            redQ[w * ROWS + r] = sumq[j];
        }
    }
    __syncthreads();
    if (tid < ROWS) {
        float S = 0.f, Q = 0.f;
#pragma unroll
        for (int ww = 0; ww < 8; ++ww) {
            S += redS[ww * ROWS + tid];
            Q += redQ[ww * ROWS + tid];
        }
        float mean = S * (1.0f / (float)H);
        float var  = Q * (1.0f / (float)H) - mean * mean;
        statsM[tid] = mean;
        statsR[tid] = rsqrtf(var + 1e-5f);
    }
    __syncthreads();

    // ---- normalize + write out (coalesced float4 x2 per thread-chunk)
#pragma unroll
    for (int i = 0; i < 6; ++i) {
        int c  = tid + NTHREADS * i;
        int r  = c / 192;
        int c8 = c - r * 192;
        int col = c8 * 8;
        f16x8 yv = *reinterpret_cast<const f16x8*>(&hsb[r * H + (col ^ ((r & 7) << 3))]);
        float mean = statsM[r];
        float rstd = statsR[r];
        const float4* gp = reinterpret_cast<const float4*>(gamma + col);
        const float4* bp = reinterpret_cast<const float4*>(beta + col);
        float4 g0 = gp[0], g1 = gp[1];
        float4 b0 = bp[0], b1 = bp[1];
        float4 o0, o1;
        o0.x = ((float)yv[0] - mean) * rstd * g0.x + b0.x;
        o0.y = ((float)yv[1] - mean) * rstd * g0.y + b0.y;
        o0.z = ((float)yv[2] - mean) * rstd * g0.z + b0.z;
        o0.w = ((float)yv[3] - mean) * rstd * g0.w + b0.w;
        o1.x = ((float)yv[4] - mean) * rstd * g1.x + b1.x;
        o1.y = ((float)yv[5] - mean) * rstd * g1.y + b1.y;
        o1.z = ((float)yv[6] - mean) * rstd * g1.z + b1.z;
        o1.w = ((float)yv[7] - mean) * rstd * g1.w + b1.w;
        float4* op = reinterpret_cast<float4*>(out + (row0 + r) * H + col);
        op[0] = o0;
        op[1] = o1;
    }
}

extern "C" void kernel_launch(void* const* d_in, const int* in_sizes, int n_in,
                              void* d_out, int out_size, void* d_ws, size_t ws_size,
                              hipStream_t stream) {
    const float* hs    = (const float*)d_in[0];
    const float* wd    = (const float*)d_in[1];
    const float* wu    = (const float*)d_in[2];
    const float* gam   = (const float*)d_in[3];
    const float* bet   = (const float*)d_in[4];
    float* out = (float*)d_out;

    _Float16* wdp = (_Float16*)d_ws;
    _Float16* wup = (_Float16*)((char*)d_ws + (size_t)128 * H * sizeof(_Float16));

    pack_weights<<<192, 256, 0, stream>>>(wd, wu, wdp, wup);
    fused_adapter<<<NBLOCKS, NTHREADS, 0, stream>>>(hs, wdp, wup, gam, bet, out);
}